// Round 8
// baseline (87.732 us; speedup 1.0000x reference)
//
#include <hip/hip_runtime.h>
#include <math.h>

// EM-routing class-capsule layer, MI355X (gfx950).
// R8 = R7 (2 positions/thread, grid 512) + micro-trims:
//   (a) E-step stats packed float4 {mu, 0.5/sigma, -0.5*log(sigma), 0}
//       -> fewer DS reads per (ch,p)
//   (b) partial/rs LDS stores guarded to the low half-wave (values were
//       duplicated across half-waves) -> half the DS write traffic
//   (c) it<2 softmax moved before barrier 2 (only needs r_sum) -> overlaps
//       the barrier wait
//   (d) sum_ch beta_v and beta_a hoisted out of the loop (reassociation only)
// Semantics per position identical to passing R6/R7: bit-faithful E-step
// shift 18*(max_{c,ch} lp - ln10), same EPS placements, rcp/DPP reductions,
// sigma identity  Σr1(v-mu)^2 = Σr1v^2 - mu^2*(2-s1).

#define CI 32
#define CO 32
#define CH 18
#define NPOS 1024
#define OUT_ACT (16 * 32)     // 512 activation floats, then pose

constexpr float EPSF = 1e-9f;
constexpr float LN10 = 2.302585092994046f;

__device__ __forceinline__ float fast_rcp(float x) {
    return __builtin_amdgcn_rcpf(x);
}

template <int CTRL>
__device__ __forceinline__ float dppf(float x) {
    union { float f; int i; } u; u.f = x;
    u.i = __builtin_amdgcn_update_dpp(u.i, u.i, CTRL, 0xF, 0xF, true);
    return u.f;
}

// sum/max over each 32-lane group (lanes 0-31 and 32-63 independently).
__device__ __forceinline__ float bf_sum32(float x) {
    x += dppf<0xB1>(x);    // quad_perm xor1
    x += dppf<0x4E>(x);    // quad_perm xor2
    x += dppf<0x141>(x);   // row_half_mirror == xor4
    x += dppf<0x140>(x);   // row_mirror == xor8
    x += __shfl_xor(x, 16);
    return x;
}
__device__ __forceinline__ float bf_max32(float x) {
    x = fmaxf(x, dppf<0xB1>(x));
    x = fmaxf(x, dppf<0x4E>(x));
    x = fmaxf(x, dppf<0x141>(x));
    x = fmaxf(x, dppf<0x140>(x));
    x = fmaxf(x, __shfl_xor(x, 16));
    return x;
}

__global__ __launch_bounds__(256, 2) void caps_em_kernel(
    const float* __restrict__ x,
    const float* __restrict__ w,
    const float* __restrict__ beta_v,
    const float* __restrict__ beta_a,
    const float* __restrict__ coord_add,
    float* __restrict__ out)
{
    const int n0 = blockIdx.x * 2;
    const int t  = threadIdx.x;
    const int c  = t & 31;
    const int ig = t >> 5;            // 0..7
    const int wv = t >> 6;            // wave 0..3
    const bool lo = (t & 32) == 0;    // low half of wave

    __shared__ float  pose[2][CI][16];
    __shared__ float  act_in[2][CI];
    __shared__ float  rs_part[2][4][CO];        // per-wave rs partials
    __shared__ float2 part2[2][4][CO * 19];     // (Σrv, Σrv·v) per ch, 19-pad
    __shared__ float4 stats[2][CO * 19];        // {mu, 0.5/sig, -0.5*log(sig), 0}

    // ---- load pose + activations for both positions (coalesced) ----
    const float* xrow = x + n0 * (CI * 17);
    for (int e = t; e < 2 * CI * 17; e += 256) {
        int p = e >= CI * 17;
        int idx = e - p * (CI * 17);
        int i = idx / 17, k = idx % 17;
        float val = xrow[e];
        if (k < 16) pose[p][i][k] = val;
        else        act_in[p][i]  = val;
    }
    float cxy[2][2];
    #pragma unroll
    for (int p = 0; p < 2; ++p) {
        cxy[p][0] = coord_add[((n0 + p) & 63) * 2 + 0];
        cxy[p][1] = coord_add[((n0 + p) & 63) * 2 + 1];
    }
    // hoisted input constants for this thread's c
    float bvsum = 0.0f;
    #pragma unroll
    for (int ch = 0; ch < CH; ++ch) bvsum += beta_v[c * CH + ch];
    const float ba_c = beta_a[c];
    __syncthreads();

    // ---- votes: w-fragment loaded once per k, reused for both positions ----
    float v[2][4][16];
    #pragma unroll
    for (int k = 0; k < 4; ++k) {
        int i = ig * 4 + k;
        float wr[16];
        const float4* wp4 = (const float4*)(w + ((i * CO + c) << 4));
        #pragma unroll
        for (int q = 0; q < 4; ++q) {
            float4 wf = wp4[q];
            wr[q*4+0] = wf.x; wr[q*4+1] = wf.y; wr[q*4+2] = wf.z; wr[q*4+3] = wf.w;
        }
        #pragma unroll
        for (int p = 0; p < 2; ++p) {
            float pr[16];
            const float4* pp4 = (const float4*)pose[p][i];
            #pragma unroll
            for (int q = 0; q < 4; ++q) {
                float4 pf = pp4[q];
                pr[q*4+0] = pf.x; pr[q*4+1] = pf.y; pr[q*4+2] = pf.z; pr[q*4+3] = pf.w;
            }
            #pragma unroll
            for (int a = 0; a < 4; ++a) {
                #pragma unroll
                for (int d = 0; d < 4; ++d) {
                    float s = pr[a*4+0] * wr[0*4+d];
                    s += pr[a*4+1] * wr[1*4+d];
                    s += pr[a*4+2] * wr[2*4+d];
                    s += pr[a*4+3] * wr[3*4+d];
                    v[p][k][a*4+d] = s;
                }
            }
        }
    }

    float rr[2][4];
    float act_c[2] = {0.0f, 0.0f};
    float r_sum[2];

    for (int it = 0; it < 3; ++it) {
        if (it > 0) {
            // ---- E-step (exact reference shift), ch-outer, both positions ----
            float S[2][4], mx[2][4];
            #pragma unroll
            for (int p = 0; p < 2; ++p)
                #pragma unroll
                for (int k = 0; k < 4; ++k) { S[p][k] = 0.0f; mx[p][k] = -3.0e38f; }
            #pragma unroll
            for (int ch = 0; ch < CH; ++ch) {
                #pragma unroll
                for (int p = 0; p < 2; ++p) {
                    float4 st = stats[p][c * 19 + ch];   // {mu, q, bs, _}
                    #pragma unroll
                    for (int k = 0; k < 4; ++k) {
                        float vv = (ch == 0) ? cxy[p][0]
                                 : ((ch == 1) ? cxy[p][1] : v[p][k][ch - 2]);
                        float d  = vv - st.x;
                        float lp = st.z - d * d * st.y;
                        S[p][k] += lp;
                        mx[p][k] = fmaxf(mx[p][k], lp);
                    }
                }
            }
            #pragma unroll
            for (int k = 0; k < 4; ++k) {
                #pragma unroll
                for (int p = 0; p < 2; ++p) {
                    float m = bf_max32(mx[p][k]);      // max over (c,ch) for i
                    float shift = 18.0f * (m - LN10);
                    float pe = __expf(S[p][k] - shift);
                    float ap = pe * act_c[p];
                    float A  = bf_sum32(ap);           // sum over c
                    float invA = fast_rcp(A + EPSF);
                    float re = ap * invA;
                    float sk = A * invA;               // = sum_c re (reassoc)
                    float an = act_in[p][ig * 4 + k];
                    rr[p][k] = re * an * fast_rcp(an * sk + EPSF);
                }
            }
        } else {
            #pragma unroll
            for (int p = 0; p < 2; ++p)
                #pragma unroll
                for (int k = 0; k < 4; ++k) {
                    float an = act_in[p][ig * 4 + k];
                    rr[p][k] = (1.0f / 32.0f) * an * fast_rcp(an + EPSF);
                }
        }

        // ---- combined partials: rs + (Σrr·v, Σrr·v²), xor32-prereduced,
        //      stored by the low half-wave only (values identical) ----
        #pragma unroll
        for (int p = 0; p < 2; ++p) {
            float prr = rr[p][0] + rr[p][1] + rr[p][2] + rr[p][3];
            float prs = prr + __shfl_xor(prr, 32);
            float cx = cxy[p][0], cy = cxy[p][1];
            float s0 = cx * prr, s1 = cy * prr;
            s0 += __shfl_xor(s0, 32);
            s1 += __shfl_xor(s1, 32);
            float sv[CH], sv2[CH];
            sv[0] = s0;  sv2[0] = cx * s0;           // Σrr·cx² = cx·(Σrr·cx)
            sv[1] = s1;  sv2[1] = cy * s1;
            #pragma unroll
            for (int ch = 2; ch < CH; ++ch) {
                float s = 0.0f, s2 = 0.0f;
                #pragma unroll
                for (int k = 0; k < 4; ++k) {
                    float rv = rr[p][k] * v[p][k][ch - 2];
                    s  += rv;
                    s2 += rv * v[p][k][ch - 2];
                }
                s  += __shfl_xor(s, 32);
                s2 += __shfl_xor(s2, 32);
                sv[ch] = s; sv2[ch] = s2;
            }
            if (lo) {
                rs_part[p][wv][c] = prs;
                float2* pp = &part2[p][wv][c * 19];
                #pragma unroll
                for (int ch = 0; ch < CH; ++ch)
                    pp[ch] = make_float2(sv[ch], sv2[ch]);
            }
        }
        __syncthreads();

        // ---- distributed reduce: rs, mu, sigma -> stats; it<2 softmax here ----
        #pragma unroll
        for (int p = 0; p < 2; ++p) {
            float rs = rs_part[p][0][c] + rs_part[p][1][c]
                     + rs_part[p][2][c] + rs_part[p][3][c];
            r_sum[p] = rs;
            float rsinv = fast_rcp(rs + EPSF);
            float s1 = rs * rsinv;
            float c2 = 2.0f - s1;
            for (int ch = ig; ch < CH; ch += 8) {
                int j = c * 19 + ch;
                float2 a0 = part2[p][0][j], a1 = part2[p][1][j];
                float2 a2 = part2[p][2][j], a3 = part2[p][3][j];
                float mu_un = a0.x + a1.x + a2.x + a3.x;
                float v2_un = a0.y + a1.y + a2.y + a3.y;
                float mu  = mu_un * rsinv;
                float sig = fmaxf(v2_un * rsinv - mu * mu * c2, 0.0f) + EPSF;
                stats[p][j] = make_float4(mu, 0.5f * fast_rcp(sig),
                                          -0.5f * __logf(sig), 0.0f);
            }
        }
        if (it < 2) {
            // softmax(r_sum) over c — needs only rs, runs before barrier
            #pragma unroll
            for (int p = 0; p < 2; ++p) {
                float logit = r_sum[p];
                float mxl = bf_max32(logit);
                float ex  = __expf(logit - mxl);
                act_c[p] = ex * fast_rcp(bf_sum32(ex));
            }
        }
        __syncthreads();

        if (it == 2) {
            // final activation: cost = (Σ beta_v) - (Σ bs), then softmax
            #pragma unroll
            for (int p = 0; p < 2; ++p) {
                float bssum = 0.0f;
                #pragma unroll
                for (int ch = 0; ch < CH; ++ch)
                    bssum += stats[p][c * 19 + ch].z;
                float cost = bvsum - bssum;          // Σ(beta_v + 0.5*lsig)
                float logit = 0.03f * (ba_c - cost * r_sum[p]);  // lambda=0.03
                float mxl = bf_max32(logit);
                float ex  = __expf(logit - mxl);
                act_c[p] = ex * fast_rcp(bf_sum32(ex));
            }
        }
    }

    // ---- fused spatial mean: merged atomics (both positions, same b) ----
    const float inv64 = 1.0f / 64.0f;
    const int b = n0 >> 6;
    if (t < CO)
        atomicAdd(&out[b * CO + t], (act_c[0] + act_c[1]) * inv64);
    for (int e = t; e < CO * CH; e += 256) {
        int cc = e / CH, ch = e - cc * CH;
        float s = stats[0][cc * 19 + ch].x + stats[1][cc * 19 + ch].x;
        atomicAdd(&out[OUT_ACT + b * (CO * CH) + e], s * inv64);
    }
}

extern "C" void kernel_launch(void* const* d_in, const int* in_sizes, int n_in,
                              void* d_out, int out_size, void* d_ws, size_t ws_size,
                              hipStream_t stream) {
    const float* x         = (const float*)d_in[0];
    const float* w         = (const float*)d_in[1];
    const float* beta_v    = (const float*)d_in[2];
    const float* beta_a    = (const float*)d_in[3];
    const float* coord_add = (const float*)d_in[4];
    float* out = (float*)d_out;

    hipMemsetAsync(out, 0, (size_t)out_size * sizeof(float), stream);
    caps_em_kernel<<<dim3(NPOS / 2), dim3(256), 0, stream>>>(
        x, w, beta_v, beta_a, coord_add, out);
}

// Round 9
// 84.798 us; speedup vs baseline: 1.0346x; 1.0346x over previous
//
#include <hip/hip_runtime.h>
#include <math.h>

// EM-routing class-capsule layer, MI355X (gfx950).
// R9 = R7 base (84.2 us, conflicts ~0) + three provably-safe trims:
//   (1) it<2 softmax moved before barrier 2 (needs only r_sum)
//   (2) sum_ch beta_v / beta_a hoisted out of the loop (reassociation only)
//   (3) coord-channel lp computed once per position (bit-identical across k)
// R8's float4 stats layout + lo-guard REVERTED: float4 stride-76-word reads
// caused 4-way bank conflicts (SQ_LDS_BANK_CONFLICT 0 -> 514K, em 40->44 us).
// Semantics per position identical to passing R6/R7: bit-faithful E-step
// shift 18*(max_{c,ch} lp - ln10), same EPS placements, rcp/DPP reductions,
// sigma identity  sum r1(v-mu)^2 = sum r1 v^2 - mu^2*(2-s1).

#define CI 32
#define CO 32
#define CH 18
#define NPOS 1024
#define OUT_ACT (16 * 32)     // 512 activation floats, then pose

constexpr float EPSF = 1e-9f;
constexpr float LN10 = 2.302585092994046f;

__device__ __forceinline__ float fast_rcp(float x) {
    return __builtin_amdgcn_rcpf(x);
}

template <int CTRL>
__device__ __forceinline__ float dppf(float x) {
    union { float f; int i; } u; u.f = x;
    u.i = __builtin_amdgcn_update_dpp(u.i, u.i, CTRL, 0xF, 0xF, true);
    return u.f;
}

// sum/max over each 32-lane group (lanes 0-31 and 32-63 independently).
__device__ __forceinline__ float bf_sum32(float x) {
    x += dppf<0xB1>(x);    // quad_perm xor1
    x += dppf<0x4E>(x);    // quad_perm xor2
    x += dppf<0x141>(x);   // row_half_mirror == xor4
    x += dppf<0x140>(x);   // row_mirror == xor8
    x += __shfl_xor(x, 16);
    return x;
}
__device__ __forceinline__ float bf_max32(float x) {
    x = fmaxf(x, dppf<0xB1>(x));
    x = fmaxf(x, dppf<0x4E>(x));
    x = fmaxf(x, dppf<0x141>(x));
    x = fmaxf(x, dppf<0x140>(x));
    x = fmaxf(x, __shfl_xor(x, 16));
    return x;
}

__global__ __launch_bounds__(256, 2) void caps_em_kernel(
    const float* __restrict__ x,
    const float* __restrict__ w,
    const float* __restrict__ beta_v,
    const float* __restrict__ beta_a,
    const float* __restrict__ coord_add,
    float* __restrict__ out)
{
    const int n0 = blockIdx.x * 2;
    const int t  = threadIdx.x;
    const int c  = t & 31;
    const int ig = t >> 5;            // 0..7
    const int wv = t >> 6;            // wave 0..3

    __shared__ float  pose[2][CI][16];
    __shared__ float  act_in[2][CI];
    __shared__ float  rs_part[2][4][CO];        // per-wave rs partials
    __shared__ float2 part2[2][4][CO * 19];     // (Σrv, Σrv·v) per ch, 19-pad
    __shared__ float2 muq_s[2][CO * 19];        // {mu, 0.5/sigma}
    __shared__ float  base_s[2][CO * 19];       // -0.5*log(sigma)

    // ---- load pose + activations for both positions (coalesced) ----
    const float* xrow = x + n0 * (CI * 17);
    for (int e = t; e < 2 * CI * 17; e += 256) {
        int p = e >= CI * 17;
        int idx = e - p * (CI * 17);
        int i = idx / 17, k = idx % 17;
        float val = xrow[e];
        if (k < 16) pose[p][i][k] = val;
        else        act_in[p][i]  = val;
    }
    float cxy[2][2];
    #pragma unroll
    for (int p = 0; p < 2; ++p) {
        cxy[p][0] = coord_add[((n0 + p) & 63) * 2 + 0];
        cxy[p][1] = coord_add[((n0 + p) & 63) * 2 + 1];
    }
    // hoisted per-c constants (reassociation only)
    float bvsum = 0.0f;
    #pragma unroll
    for (int ch = 0; ch < CH; ++ch) bvsum += beta_v[c * CH + ch];
    const float ba_c = beta_a[c];
    __syncthreads();

    // ---- votes: w-fragment loaded once per k, reused for both positions ----
    float v[2][4][16];
    #pragma unroll
    for (int k = 0; k < 4; ++k) {
        int i = ig * 4 + k;
        float wr[16];
        const float4* wp4 = (const float4*)(w + ((i * CO + c) << 4));
        #pragma unroll
        for (int q = 0; q < 4; ++q) {
            float4 wf = wp4[q];
            wr[q*4+0] = wf.x; wr[q*4+1] = wf.y; wr[q*4+2] = wf.z; wr[q*4+3] = wf.w;
        }
        #pragma unroll
        for (int p = 0; p < 2; ++p) {
            float pr[16];
            const float4* pp4 = (const float4*)pose[p][i];
            #pragma unroll
            for (int q = 0; q < 4; ++q) {
                float4 pf = pp4[q];
                pr[q*4+0] = pf.x; pr[q*4+1] = pf.y; pr[q*4+2] = pf.z; pr[q*4+3] = pf.w;
            }
            #pragma unroll
            for (int a = 0; a < 4; ++a) {
                #pragma unroll
                for (int d = 0; d < 4; ++d) {
                    float s = pr[a*4+0] * wr[0*4+d];
                    s += pr[a*4+1] * wr[1*4+d];
                    s += pr[a*4+2] * wr[2*4+d];
                    s += pr[a*4+3] * wr[3*4+d];
                    v[p][k][a*4+d] = s;
                }
            }
        }
    }

    float rr[2][4];
    float act_c[2] = {0.0f, 0.0f};
    float r_sum[2];

    for (int it = 0; it < 3; ++it) {
        if (it > 0) {
            // ---- E-step (exact reference shift), ch-outer, both positions ----
            // coord-channel lp is identical across k: compute once per p,
            // seed S/mx with it (same accumulation order -> bit-exact).
            float S[2][4], mx[2][4];
            #pragma unroll
            for (int p = 0; p < 2; ++p) {
                float2 mq0 = muq_s[p][c * 19 + 0];
                float  b0  = base_s[p][c * 19 + 0];
                float2 mq1 = muq_s[p][c * 19 + 1];
                float  b1  = base_s[p][c * 19 + 1];
                float d0 = cxy[p][0] - mq0.x;
                float lp0 = b0 - d0 * d0 * mq0.y;
                float d1 = cxy[p][1] - mq1.x;
                float lp1 = b1 - d1 * d1 * mq1.y;
                float s01 = lp0 + lp1;
                float m01 = fmaxf(lp0, lp1);
                #pragma unroll
                for (int k = 0; k < 4; ++k) { S[p][k] = s01; mx[p][k] = m01; }
            }
            #pragma unroll
            for (int ch = 2; ch < CH; ++ch) {
                #pragma unroll
                for (int p = 0; p < 2; ++p) {
                    float2 mq = muq_s[p][c * 19 + ch];
                    float  bs = base_s[p][c * 19 + ch];
                    #pragma unroll
                    for (int k = 0; k < 4; ++k) {
                        float d  = v[p][k][ch - 2] - mq.x;
                        float lp = bs - d * d * mq.y;
                        S[p][k] += lp;
                        mx[p][k] = fmaxf(mx[p][k], lp);
                    }
                }
            }
            #pragma unroll
            for (int k = 0; k < 4; ++k) {
                #pragma unroll
                for (int p = 0; p < 2; ++p) {
                    float m = bf_max32(mx[p][k]);      // max over (c,ch) for i
                    float shift = 18.0f * (m - LN10);
                    float pe = __expf(S[p][k] - shift);
                    float ap = pe * act_c[p];
                    float A  = bf_sum32(ap);           // sum over c
                    float invA = fast_rcp(A + EPSF);
                    float re = ap * invA;
                    float sk = A * invA;               // = sum_c re (reassoc)
                    float an = act_in[p][ig * 4 + k];
                    rr[p][k] = re * an * fast_rcp(an * sk + EPSF);
                }
            }
        } else {
            #pragma unroll
            for (int p = 0; p < 2; ++p)
                #pragma unroll
                for (int k = 0; k < 4; ++k) {
                    float an = act_in[p][ig * 4 + k];
                    rr[p][k] = (1.0f / 32.0f) * an * fast_rcp(an + EPSF);
                }
        }

        // ---- combined partials: rs + (Σrr·v, Σrr·v²) pairs, xor32-prereduced ----
        #pragma unroll
        for (int p = 0; p < 2; ++p) {
            float prr = rr[p][0] + rr[p][1] + rr[p][2] + rr[p][3];
            float prs = prr + __shfl_xor(prr, 32);
            rs_part[p][wv][c] = prs;                 // both halves: same value
            float2* pp = &part2[p][wv][c * 19];
            float cx = cxy[p][0], cy = cxy[p][1];
            float s0 = cx * prr, s1 = cy * prr;
            s0 += __shfl_xor(s0, 32);
            s1 += __shfl_xor(s1, 32);
            pp[0] = make_float2(s0, cx * s0);        // Σrr·cx² = cx·(Σrr·cx)
            pp[1] = make_float2(s1, cy * s1);
            #pragma unroll
            for (int ch = 2; ch < CH; ++ch) {
                float s = 0.0f, s2 = 0.0f;
                #pragma unroll
                for (int k = 0; k < 4; ++k) {
                    float rv = rr[p][k] * v[p][k][ch - 2];
                    s  += rv;
                    s2 += rv * v[p][k][ch - 2];
                }
                s  += __shfl_xor(s, 32);
                s2 += __shfl_xor(s2, 32);
                pp[ch] = make_float2(s, s2);
            }
        }
        __syncthreads();

        // ---- distributed reduce: rs, mu, sigma -> {mu,q} + base ----
        #pragma unroll
        for (int p = 0; p < 2; ++p) {
            float rs = rs_part[p][0][c] + rs_part[p][1][c]
                     + rs_part[p][2][c] + rs_part[p][3][c];
            r_sum[p] = rs;
            float rsinv = fast_rcp(rs + EPSF);
            float s1 = rs * rsinv;
            float c2 = 2.0f - s1;
            for (int ch = ig; ch < CH; ch += 8) {
                int j = c * 19 + ch;
                float2 a0 = part2[p][0][j], a1 = part2[p][1][j];
                float2 a2 = part2[p][2][j], a3 = part2[p][3][j];
                float mu_un = a0.x + a1.x + a2.x + a3.x;
                float v2_un = a0.y + a1.y + a2.y + a3.y;
                float mu  = mu_un * rsinv;
                float sig = fmaxf(v2_un * rsinv - mu * mu * c2, 0.0f) + EPSF;
                muq_s[p][j]  = make_float2(mu, 0.5f * fast_rcp(sig));
                base_s[p][j] = -0.5f * __logf(sig);
            }
        }
        if (it < 2) {
            // softmax(r_sum) over c — needs only rs, overlaps barrier wait
            #pragma unroll
            for (int p = 0; p < 2; ++p) {
                float logit = r_sum[p];
                float mxl = bf_max32(logit);
                float ex  = __expf(logit - mxl);
                act_c[p] = ex * fast_rcp(bf_sum32(ex));
            }
        }
        __syncthreads();

        if (it == 2) {
            // final activation: cost = (Σ beta_v) - (Σ base), then softmax
            #pragma unroll
            for (int p = 0; p < 2; ++p) {
                float bssum = 0.0f;
                #pragma unroll
                for (int ch = 0; ch < CH; ++ch)
                    bssum += base_s[p][c * 19 + ch];
                float cost = bvsum - bssum;          // Σ(beta_v + 0.5*lsig)
                float logit = 0.03f * (ba_c - cost * r_sum[p]);  // lambda=0.03
                float mxl = bf_max32(logit);
                float ex  = __expf(logit - mxl);
                act_c[p] = ex * fast_rcp(bf_sum32(ex));
            }
        }
    }

    // ---- fused spatial mean: merged atomics (both positions, same b) ----
    const float inv64 = 1.0f / 64.0f;
    const int b = n0 >> 6;
    if (t < CO)
        atomicAdd(&out[b * CO + t], (act_c[0] + act_c[1]) * inv64);
    for (int e = t; e < CO * CH; e += 256) {
        int cc = e / CH, ch = e - cc * CH;
        float s = muq_s[0][cc * 19 + ch].x + muq_s[1][cc * 19 + ch].x;
        atomicAdd(&out[OUT_ACT + b * (CO * CH) + e], s * inv64);
    }
}

extern "C" void kernel_launch(void* const* d_in, const int* in_sizes, int n_in,
                              void* d_out, int out_size, void* d_ws, size_t ws_size,
                              hipStream_t stream) {
    const float* x         = (const float*)d_in[0];
    const float* w         = (const float*)d_in[1];
    const float* beta_v    = (const float*)d_in[2];
    const float* beta_a    = (const float*)d_in[3];
    const float* coord_add = (const float*)d_in[4];
    float* out = (float*)d_out;

    hipMemsetAsync(out, 0, (size_t)out_size * sizeof(float), stream);
    caps_em_kernel<<<dim3(NPOS / 2), dim3(256), 0, stream>>>(
        x, w, beta_v, beta_a, coord_add, out);
}